// Round 10
// baseline (206.366 us; speedup 1.0000x reference)
//
#include <hip/hip_runtime.h>
#include <hip/hip_bf16.h>
#include <stdint.h>

#define P_TOT   4096
#define N_CODE  16384
#define DIM     256
#define HW      1024
#define CHW     262144
#define NBLK    16        // 16384 / 1024 codes per wg-chunk

typedef unsigned long long u64;
typedef unsigned short u16;
typedef __attribute__((ext_vector_type(4))) float f32x4;
typedef __attribute__((ext_vector_type(8))) short bf16x8;
typedef __attribute__((ext_vector_type(8))) unsigned short ushort8;

#define FENCE() asm volatile("" ::: "memory")
#define BAR()   __builtin_amdgcn_s_barrier()
#define VM(n)   asm volatile("s_waitcnt vmcnt(" #n ")" ::: "memory")

__device__ __forceinline__ unsigned int mono(float f) {
  unsigned int u = __float_as_uint(f);
  return (u & 0x80000000u) ? ~u : (u | 0x80000000u);
}
__device__ __forceinline__ u16 f2bf(float f) {
  __hip_bfloat16 h = __float2bfloat16(f);
  return *(u16*)&h;
}
__device__ __forceinline__ float bf2f(u16 b) {
  __hip_bfloat16 h = *(__hip_bfloat16*)&b;
  return __bfloat162float(h);
}
__device__ __forceinline__ void gload16(const void* g, void* l) {
  __builtin_amdgcn_global_load_lds(
      (const __attribute__((address_space(1))) unsigned int*)g,
      (__attribute__((address_space(3))) unsigned int*)l, 16, 0, 0);
}

// ================== merged prep: split_cb | split_x (+fp32 transpose) | cnorm | wt ==================
// bfrag unit [(nb*8+kt)*4+bq] of 4096 u16: [h(2)][s(4)][row64][8elem]
// xfrag unit [(mbO*8+kt)*4+aq] same internal layout (rows = pixels)
// xt[4096][256] fp32 transposed latent (coalesced refinement reads)
__global__ __launch_bounds__(256) void k_prep(const float* __restrict__ cb,
                                              const float* __restrict__ latent,
                                              const float* __restrict__ dec_w,
                                              u16* __restrict__ bfrag,
                                              u16* __restrict__ xfrag,
                                              float* __restrict__ xt,
                                              float* __restrict__ cnorm,
                                              float* __restrict__ wt) {
  __shared__ float ls[64][68];
  int bid = blockIdx.x;
  int t = threadIdx.x;
  if (bid < 1024) {
    int blk = bid;                   // nb(64) x bq(4) x kp(4)
    int kp = blk & 3, bq = (blk >> 2) & 3, nb = blk >> 4;
    int code0 = nb * 256 + bq * 64;
    int k0 = kp * 64;
    int lr = t >> 4, lc = (t & 15) * 4;
    #pragma unroll
    for (int pss = 0; pss < 4; ++pss) {
      int row = pss * 16 + lr;
      float4 v = *(const float4*)&cb[(size_t)(code0 + row) * DIM + k0 + lc];
      ls[row][lc] = v.x; ls[row][lc + 1] = v.y; ls[row][lc + 2] = v.z; ls[row][lc + 3] = v.w;
    }
    __syncthreads();
    int row64 = t & 63, g = t >> 6;
    #pragma unroll
    for (int it = 0; it < 4; ++it) {
      int combo = it * 4 + g;        // kt2*8 + s*2 + h
      int kt2 = combo >> 3, s = (combo >> 1) & 3, h = combo & 1;
      int kt = kp * 2 + kt2;
      ushort8 o;
      #pragma unroll
      for (int e = 0; e < 8; ++e) {
        float x = ls[row64][kt2 * 32 + s * 8 + e];
        u16 hi = f2bf(x);
        o[e] = h ? f2bf(x - bf2f(hi)) : hi;
      }
      size_t unitIdx = (size_t)(nb * 8 + kt) * 4 + bq;
      *(ushort8*)&bfrag[unitIdx * 4096 + (size_t)((h * 4 + s) * 64 + row64) * 8] = o;
    }
  } else if (bid < 1280) {
    int blk = bid - 1024;            // rowblk(64) x kp(4)
    int kp = blk & 3, rowblk = blk >> 2;
    int g0 = rowblk * 64;
    int b = g0 >> 10, hw0 = g0 & 1023;
    int c0 = kp * 64;
    int ch = t >> 4, px4 = (t & 15) * 4;
    #pragma unroll
    for (int pss = 0; pss < 4; ++pss) {
      int c = pss * 16 + ch;
      float4 v = *(const float4*)&latent[(size_t)b * CHW + (size_t)(c0 + c) * HW + hw0 + px4];
      ls[px4 + 0][c] = v.x; ls[px4 + 1][c] = v.y; ls[px4 + 2][c] = v.z; ls[px4 + 3][c] = v.w;
    }
    __syncthreads();
    int row64 = t & 63, g = t >> 6;
    #pragma unroll
    for (int it = 0; it < 4; ++it) {
      int combo = it * 4 + g;
      int kt2 = combo >> 3, s = (combo >> 1) & 3, h = combo & 1;
      int kt = kp * 2 + kt2;
      ushort8 o;
      #pragma unroll
      for (int e = 0; e < 8; ++e) {
        float x = ls[row64][kt2 * 32 + s * 8 + e];
        u16 hi = f2bf(x);
        o[e] = h ? f2bf(x - bf2f(hi)) : hi;
      }
      int mbO = rowblk >> 2, aq = rowblk & 3;
      size_t unitIdx = (size_t)(mbO * 8 + kt) * 4 + aq;
      *(ushort8*)&xfrag[unitIdx * 4096 + (size_t)((h * 4 + s) * 64 + row64) * 8] = o;
    }
    // fp32 transposed latent for k_idx refinement
    int pix = t >> 2, sub = t & 3;   // 64 pixels x 4 threads
    #pragma unroll
    for (int q = 0; q < 4; ++q) {
      int c = sub * 16 + q * 4;
      float4 v;
      v.x = ls[pix][c]; v.y = ls[pix][c + 1]; v.z = ls[pix][c + 2]; v.w = ls[pix][c + 3];
      *(float4*)&xt[(size_t)(g0 + pix) * DIM + c0 + c] = v;
    }
  } else if (bid < 5376) {
    int code = (bid - 1280) * 4 + (t >> 6);
    int lane = t & 63;
    float4 v = ((const float4*)(cb + (size_t)code * DIM))[lane];
    float sv = fmaf(v.x, v.x, fmaf(v.y, v.y, fmaf(v.z, v.z, v.w * v.w)));
    #pragma unroll
    for (int off = 32; off; off >>= 1) sv += __shfl_down(sv, off, 64);
    if (lane == 0) cnorm[code] = sv;
  } else {
    int e = (bid - 5376) * 256 + t;
    if (e < 6912) {
      int ic = e & 255; int r = e >> 8;
      int kx = r % 3; r /= 3; int ky = r % 3; int oc = r / 3;
      wt[e] = dec_w[((oc * 256 + ic) * 3 + ky) * 3 + kx];
    }
  }
}

// ================== main VQ: 256x256 tile, wave-tile 128x64 (LDS-traffic-minimal) ==================
// Grid 256 = 1 wg/CU. 8 waves as 2(wr) x 4(wc). Wm=128, Wn=64.
// LDS reads per wave-tile = (128+64)*32*4B = 24KB (vs 36KB @ R9's 32x256) -> 3x less per CU.
__global__ __launch_bounds__(512, 2) void k_vq(const u16* __restrict__ xfrag,
                                               const u16* __restrict__ bfrag,
                                               const float* __restrict__ cnorm,
                                               u64* __restrict__ partial) {
  __shared__ u16 lds[2][2][4][4096];   // [buf][A/B][unit][8KB] = 128 KiB
  __shared__ float cnl[1024];          // 4 KB
  __shared__ u64 red[256][4];          // 8 KB per-row/per-wc argmin table

  int bid = blockIdx.x;                // 256 wgs = 1/CU
  int xcd = bid & 7, ix = bid >> 3;    // 32 per XCD
  int nbc = xcd * 2 + (ix >> 4);       // 0..15 (1024-code chunk; 2 chunks/XCD -> 2MB B in L2)
  int mb  = ix & 15;                   // 0..15 (256-row X block)

  int tid = threadIdx.x, lane = tid & 63, w = tid >> 6;
  int fr = lane & 15, s = lane >> 4;
  int wr = w >> 2, wc = w & 3;         // wave grid 2m x 4n
  int tid8 = tid * 8;

  const u16* Xb = xfrag + (size_t)mb * 32 * 4096;    // 8 kt x 4 aq units
  const u16* Bb = bfrag + (size_t)nbc * 128 * 4096;  // 32 tiles x 4 units, contiguous

  // cnorm chunk -> LDS, red init (drained by __syncthreads before staging)
  cnl[tid]       = cnorm[nbc * 1024 + tid];
  cnl[tid + 512] = cnorm[nbc * 1024 + 512 + tid];
  ((u64*)red)[tid]       = ~0ull;
  ((u64*)red)[tid + 512] = ~0ull;
  __syncthreads();

  // ---- prologue: stage tile 0 fully ----
  #pragma unroll
  for (int r = 0; r < 4; ++r) gload16(Xb + (size_t)r * 4096 + tid8, &lds[0][0][r][0] + tid8);
  #pragma unroll
  for (int r = 0; r < 4; ++r) gload16(Bb + (size_t)r * 4096 + tid8, &lds[0][1][r][0] + tid8);
  VM(0); BAR(); FENCE();

  f32x4 acc[8][4] = {};

  #define FOLD(pp) {                                                          \
    float cnv[4]; unsigned codev[4];                                          \
    _Pragma("unroll")                                                         \
    for (int nf = 0; nf < 4; ++nf) {                                          \
      cnv[nf] = cnl[(pp) * 256 + wc * 64 + nf * 16 + fr];                     \
      codev[nf] = (unsigned)(nbc * 1024 + (pp) * 256 + wc * 64 + nf * 16 + fr); \
    }                                                                         \
    _Pragma("unroll")                                                         \
    for (int mfr = 0; mfr < 8; ++mfr) {                                       \
      u64 bb[4];                                                              \
      _Pragma("unroll")                                                       \
      for (int rr = 0; rr < 4; ++rr) {                                        \
        u64 m = ~0ull;                                                        \
        _Pragma("unroll")                                                     \
        for (int nf = 0; nf < 4; ++nf) {                                      \
          float val = fmaf(-2.0f, acc[mfr][nf][rr], cnv[nf]);                 \
          u64 key = ((u64)mono(val) << 32) | codev[nf];                       \
          if (key < m) m = key;                                               \
        }                                                                     \
        bb[rr] = m;                                                           \
      }                                                                       \
      _Pragma("unroll")                                                       \
      for (int d = 1; d < 16; d <<= 1) {                                      \
        _Pragma("unroll")                                                     \
        for (int rr = 0; rr < 4; ++rr) {                                      \
          u64 o = __shfl_xor(bb[rr], d, 64);                                  \
          if (o < bb[rr]) bb[rr] = o;                                         \
        }                                                                     \
      }                                                                       \
      if (fr == 0) {                                                          \
        _Pragma("unroll")                                                     \
        for (int rr = 0; rr < 4; ++rr) {                                      \
          int row = wr * 128 + mfr * 16 + s * 4 + rr;                         \
          u64 old = red[row][wc];                                             \
          red[row][wc] = (bb[rr] < old) ? bb[rr] : old;                       \
        }                                                                     \
      }                                                                       \
      _Pragma("unroll")                                                       \
      for (int nf = 0; nf < 4; ++nf)                                          \
        _Pragma("unroll")                                                     \
        for (int rr = 0; rr < 4; ++rr) acc[mfr][nf][rr] = 0.0f;               \
    }                                                                         \
  }

  // ---- 32 K-tiles (4 panels x 8 kt), ONE barrier-pair each (R9-proven sync) ----
  #pragma unroll 1
  for (int tt = 0; tt < 32; ++tt) {
    const int cur = tt & 1, nxt = cur ^ 1;
    const int kt = tt & 7;
    const u16* LA = &lds[cur][0][0][0];
    const u16* LB = &lds[cur][1][0][0];
    if (tt < 31) {
      const u16* SA = Xb + (size_t)((tt + 1) & 7) * 16384;
      const u16* SB = Bb + (size_t)(tt + 1) * 16384;
      #pragma unroll
      for (int r = 0; r < 4; ++r) gload16(SA + (size_t)r * 4096 + tid8, &lds[nxt][0][r][0] + tid8);
      #pragma unroll
      for (int r = 0; r < 4; ++r) gload16(SB + (size_t)r * 4096 + tid8, &lds[nxt][1][r][0] + tid8);
    }
    // B fragments: Wn=64 -> 4 n-frags, read ONCE, reused across 8 m-frags
    bf16x8 bh[4], bl[4];
    #pragma unroll
    for (int nf = 0; nf < 4; ++nf) {
      bh[nf] = *(const bf16x8*)&LB[wc * 4096 + (size_t)((0 + s) * 64 + nf * 16 + fr) * 8];
      bl[nf] = *(const bf16x8*)&LB[wc * 4096 + (size_t)((4 + s) * 64 + nf * 16 + fr) * 8];
    }
    #pragma unroll
    for (int mfr = 0; mfr < 8; ++mfr) {
      const int au = wr * 2 + (mfr >> 2);
      const int r64 = (mfr & 3) * 16 + fr;
      bf16x8 ah = *(const bf16x8*)&LA[au * 4096 + (size_t)((0 + s) * 64 + r64) * 8];
      bf16x8 al = *(const bf16x8*)&LA[au * 4096 + (size_t)((4 + s) * 64 + r64) * 8];
      __builtin_amdgcn_s_setprio(1);
      #pragma unroll
      for (int nf = 0; nf < 4; ++nf)
        acc[mfr][nf] = __builtin_amdgcn_mfma_f32_16x16x32_bf16(ah, bh[nf], acc[mfr][nf], 0, 0, 0);
      #pragma unroll
      for (int nf = 0; nf < 4; ++nf)
        acc[mfr][nf] = __builtin_amdgcn_mfma_f32_16x16x32_bf16(ah, bl[nf], acc[mfr][nf], 0, 0, 0);
      #pragma unroll
      for (int nf = 0; nf < 4; ++nf)
        acc[mfr][nf] = __builtin_amdgcn_mfma_f32_16x16x32_bf16(al, bh[nf], acc[mfr][nf], 0, 0, 0);
      __builtin_amdgcn_s_setprio(0);
    }
    if (kt == 7) { FOLD(tt >> 3); }
    VM(0);
    BAR(); FENCE();
  }

  // ---- final: reduce red over wc, write per-row minimum ----
  if (tid < 256) {
    u64 m0 = red[tid][0], m1 = red[tid][1], m2 = red[tid][2], m3 = red[tid][3];
    u64 a = m0 < m1 ? m0 : m1;
    u64 b2 = m2 < m3 ? m2 : m3;
    partial[(size_t)(mb * 256 + tid) * NBLK + nbc] = a < b2 ? a : b2;
  }
}

// ---- per-pixel top-2 reduce + exact fp64 refinement (1 wave/pixel, coalesced) ----
__global__ __launch_bounds__(256) void k_idx(const u64* __restrict__ partial,
                                             const float* __restrict__ xt,
                                             const float* __restrict__ cb,
                                             int* __restrict__ idxo) {
  int p = (blockIdx.x * 256 + threadIdx.x) >> 6;   // pixel id, 1 wave each
  int lane = threadIdx.x & 63;
  u64 v = (lane < NBLK) ? partial[(size_t)p * NBLK + lane] : ~0ull;
  u64 m1 = v;
  #pragma unroll
  for (int d = 1; d < 64; d <<= 1) { u64 o = __shfl_xor(m1, d, 64); if (o < m1) m1 = o; }
  u64 vv = (v == m1) ? ~0ull : v;
  u64 m2 = vv;
  #pragma unroll
  for (int d = 1; d < 64; d <<= 1) { u64 o = __shfl_xor(m2, d, 64); if (o < m2) m2 = o; }
  int n1 = (int)(m1 & 0xFFFFFFFFull);
  int n2 = (int)(m2 & 0xFFFFFFFFull);

  float4 xv = *(const float4*)&xt[(size_t)p * DIM + lane * 4];
  float4 ca = *(const float4*)&cb[(size_t)n1 * DIM + lane * 4];
  float4 cbv = *(const float4*)&cb[(size_t)n2 * DIM + lane * 4];
  double d1, d2;
  {
    double e0 = (double)xv.x - (double)ca.x, e1 = (double)xv.y - (double)ca.y;
    double e2 = (double)xv.z - (double)ca.z, e3 = (double)xv.w - (double)ca.w;
    d1 = e0 * e0 + e1 * e1 + e2 * e2 + e3 * e3;
  }
  {
    double e0 = (double)xv.x - (double)cbv.x, e1 = (double)xv.y - (double)cbv.y;
    double e2 = (double)xv.z - (double)cbv.z, e3 = (double)xv.w - (double)cbv.w;
    d2 = e0 * e0 + e1 * e1 + e2 * e2 + e3 * e3;
  }
  #pragma unroll
  for (int d = 32; d; d >>= 1) {
    d1 += __shfl_down(d1, d, 64);
    d2 += __shfl_down(d2, d, 64);
  }
  if (lane == 0) {
    idxo[p] = (d2 < d1 || (d2 == d1 && n2 < n1)) ? n2 : n1;
  }
}

// ---- gather + 3x3 conv + bias + (x+1)*0.5 + clamp ----
__global__ __launch_bounds__(256) void k_conv(const int* __restrict__ idxo,
                                              const float* __restrict__ cb,
                                              const float* __restrict__ wt,
                                              const float* __restrict__ bias,
                                              float* __restrict__ out) {
  __shared__ int idxl[3][32];
  int y = blockIdx.x, b = blockIdx.y;
  int t = threadIdx.x;
  if (t < 96) {
    int r = t >> 5, px = t & 31;
    int yy = min(max(y + r - 1, 0), 31);
    idxl[r][px] = idxo[b * HW + yy * 32 + px];
  }
  __syncthreads();

  int x = t & 31, icg = t >> 5;
  float a0 = 0.f, a1 = 0.f, a2 = 0.f;
  #pragma unroll
  for (int dy = -1; dy <= 1; dy++) {
    int yy = y + dy;
    if (yy < 0 || yy >= 32) continue;
    #pragma unroll
    for (int dx = -1; dx <= 1; dx++) {
      int xx = x + dx;
      if (xx < 0 || xx >= 32) continue;
      int n = idxl[dy + 1][xx];
      const float4* crow = (const float4*)(cb + (size_t)n * DIM + icg * 32);
      int tap = (dy + 1) * 3 + (dx + 1);
      const float4* w0p = (const float4*)(wt + (size_t)(0 * 9 + tap) * DIM + icg * 32);
      const float4* w1p = (const float4*)(wt + (size_t)(1 * 9 + tap) * DIM + icg * 32);
      const float4* w2p = (const float4*)(wt + (size_t)(2 * 9 + tap) * DIM + icg * 32);
      #pragma unroll
      for (int q = 0; q < 8; q++) {
        float4 qv = crow[q];
        float4 wa = w0p[q];
        a0 = fmaf(qv.x, wa.x, a0); a0 = fmaf(qv.y, wa.y, a0);
        a0 = fmaf(qv.z, wa.z, a0); a0 = fmaf(qv.w, wa.w, a0);
        float4 wb = w1p[q];
        a1 = fmaf(qv.x, wb.x, a1); a1 = fmaf(qv.y, wb.y, a1);
        a1 = fmaf(qv.z, wb.z, a1); a1 = fmaf(qv.w, wb.w, a1);
        float4 wcv = w2p[q];
        a2 = fmaf(qv.x, wcv.x, a2); a2 = fmaf(qv.y, wcv.y, a2);
        a2 = fmaf(qv.z, wcv.z, a2); a2 = fmaf(qv.w, wcv.w, a2);
      }
    }
  }
  __shared__ float red[3][32][8];
  red[0][x][icg] = a0; red[1][x][icg] = a1; red[2][x][icg] = a2;
  __syncthreads();
  if (t < 96) {
    int oc = t >> 5, xo = t & 31;
    float sum = 0.f;
    #pragma unroll
    for (int k = 0; k < 8; k++) sum += red[oc][xo][k];
    sum += bias[oc];
    sum = (sum + 1.0f) * 0.5f;
    sum = fminf(fmaxf(sum, 0.0f), 1.0f);
    out[((size_t)(b * 3 + oc) * 32 + y) * 32 + xo] = sum;
  }
}

extern "C" void kernel_launch(void* const* d_in, const int* in_sizes, int n_in,
                              void* d_out, int out_size, void* d_ws, size_t ws_size,
                              hipStream_t stream) {
  const float* latent = (const float*)d_in[0];   // [4,256,32,32]
  const float* cb     = (const float*)d_in[1];   // [16384,256]
  const float* dec_w  = (const float*)d_in[2];   // [3,256,3,3]
  const float* dec_b  = (const float*)d_in[3];   // [3]
  float* out = (float*)d_out;                    // [4,3,32,32]

  char* ws = (char*)d_ws;
  u64*   partial = (u64*)ws;                      // 512 KB [4096][16]
  float* cnorm   = (float*)(ws + 0x080000);       // 64 KB
  int*   idx     = (int*)  (ws + 0x090000);       // 16 KB
  float* wt      = (float*)(ws + 0x094000);       // 27 KB
  u16*   xfrag   = (u16*)  (ws + 0x100000);       // 4 MB
  u16*   bfrag   = (u16*)  (ws + 0x800000);       // 16 MB -> 0x1800000
  float* xt      = (float*)(ws + 0x1800000);      // 4 MB  -> ends 28 MB

  k_prep<<<dim3(5403), dim3(256), 0, stream>>>(cb, latent, dec_w, bfrag, xfrag, xt, cnorm, wt);
  k_vq  <<<dim3(256),  dim3(512), 0, stream>>>(xfrag, bfrag, cnorm, partial);
  k_idx <<<dim3(1024), dim3(256), 0, stream>>>(partial, xt, cb, idx);
  k_conv<<<dim3(32, 4), dim3(256), 0, stream>>>(idx, cb, wt, dec_b, out);
}

// Round 11
// 186.596 us; speedup vs baseline: 1.1060x; 1.1060x over previous
//
#include <hip/hip_runtime.h>
#include <hip/hip_bf16.h>
#include <stdint.h>

#define P_TOT   4096
#define N_CODE  16384
#define DIM     256
#define HW      1024
#define CHW     262144
#define NBLK    16        // 16384 / 1024 codes per wg-chunk

typedef unsigned long long u64;
typedef unsigned short u16;
typedef __attribute__((ext_vector_type(4))) float f32x4;
typedef __attribute__((ext_vector_type(8))) short bf16x8;
typedef __attribute__((ext_vector_type(8))) unsigned short ushort8;

#define FENCE() asm volatile("" ::: "memory")
#define BAR()   __builtin_amdgcn_s_barrier()
#define VM(n)   asm volatile("s_waitcnt vmcnt(" #n ")" ::: "memory")
#define LGKM0() asm volatile("s_waitcnt lgkmcnt(0)" ::: "memory")

__device__ __forceinline__ unsigned int mono(float f) {
  unsigned int u = __float_as_uint(f);
  return (u & 0x80000000u) ? ~u : (u | 0x80000000u);
}
__device__ __forceinline__ u16 f2bf(float f) {
  __hip_bfloat16 h = __float2bfloat16(f);
  return *(u16*)&h;
}
__device__ __forceinline__ float bf2f(u16 b) {
  __hip_bfloat16 h = *(__hip_bfloat16*)&b;
  return __bfloat162float(h);
}
__device__ __forceinline__ void gload16(const void* g, void* l) {
  __builtin_amdgcn_global_load_lds(
      (const __attribute__((address_space(1))) unsigned int*)g,
      (__attribute__((address_space(3))) unsigned int*)l, 16, 0, 0);
}

// ================== merged prep: split_cb(+cnorm via atomics) | split_x(+xt) | wt ==================
// bfrag unit [(nb*8+kt)*4+bq] of 4096 u16: [h(2)][s(4)][row64][8elem]
// xfrag unit [(mbO*8+kt)*4+aq] same internal layout (rows = pixels)
// xt[4096][256] fp32 transposed latent (coalesced refinement reads)
__global__ __launch_bounds__(256) void k_prep(const float* __restrict__ cb,
                                              const float* __restrict__ latent,
                                              const float* __restrict__ dec_w,
                                              u16* __restrict__ bfrag,
                                              u16* __restrict__ xfrag,
                                              float* __restrict__ xt,
                                              float* __restrict__ cnorm,
                                              float* __restrict__ wt) {
  __shared__ float ls[64][68];
  int bid = blockIdx.x;
  int t = threadIdx.x;
  if (bid < 1024) {
    int blk = bid;                   // nb(64) x bq(4) x kp(4)
    int kp = blk & 3, bq = (blk >> 2) & 3, nb = blk >> 4;
    int code0 = nb * 256 + bq * 64;
    int k0 = kp * 64;
    int lr = t >> 4, lc = (t & 15) * 4;
    #pragma unroll
    for (int pss = 0; pss < 4; ++pss) {
      int row = pss * 16 + lr;
      float4 v = *(const float4*)&cb[(size_t)(code0 + row) * DIM + k0 + lc];
      ls[row][lc] = v.x; ls[row][lc + 1] = v.y; ls[row][lc + 2] = v.z; ls[row][lc + 3] = v.w;
      // fused cnorm partial (this block owns 64 ks of this code's row)
      float nrm = fmaf(v.x, v.x, fmaf(v.y, v.y, fmaf(v.z, v.z, v.w * v.w)));
      #pragma unroll
      for (int d = 1; d < 16; d <<= 1) nrm += __shfl_xor(nrm, d, 64);
      if ((t & 15) == 0) atomicAdd(&cnorm[code0 + row], nrm);
    }
    __syncthreads();
    int row64 = t & 63, g = t >> 6;
    #pragma unroll
    for (int it = 0; it < 4; ++it) {
      int combo = it * 4 + g;        // kt2*8 + s*2 + h
      int kt2 = combo >> 3, s = (combo >> 1) & 3, h = combo & 1;
      int kt = kp * 2 + kt2;
      ushort8 o;
      #pragma unroll
      for (int e = 0; e < 8; ++e) {
        float x = ls[row64][kt2 * 32 + s * 8 + e];
        u16 hi = f2bf(x);
        o[e] = h ? f2bf(x - bf2f(hi)) : hi;
      }
      size_t unitIdx = (size_t)(nb * 8 + kt) * 4 + bq;
      *(ushort8*)&bfrag[unitIdx * 4096 + (size_t)((h * 4 + s) * 64 + row64) * 8] = o;
    }
  } else if (bid < 1280) {
    int blk = bid - 1024;            // rowblk(64) x kp(4)
    int kp = blk & 3, rowblk = blk >> 2;
    int g0 = rowblk * 64;
    int b = g0 >> 10, hw0 = g0 & 1023;
    int c0 = kp * 64;
    int ch = t >> 4, px4 = (t & 15) * 4;
    #pragma unroll
    for (int pss = 0; pss < 4; ++pss) {
      int c = pss * 16 + ch;
      float4 v = *(const float4*)&latent[(size_t)b * CHW + (size_t)(c0 + c) * HW + hw0 + px4];
      ls[px4 + 0][c] = v.x; ls[px4 + 1][c] = v.y; ls[px4 + 2][c] = v.z; ls[px4 + 3][c] = v.w;
    }
    __syncthreads();
    int row64 = t & 63, g = t >> 6;
    #pragma unroll
    for (int it = 0; it < 4; ++it) {
      int combo = it * 4 + g;
      int kt2 = combo >> 3, s = (combo >> 1) & 3, h = combo & 1;
      int kt = kp * 2 + kt2;
      ushort8 o;
      #pragma unroll
      for (int e = 0; e < 8; ++e) {
        float x = ls[row64][kt2 * 32 + s * 8 + e];
        u16 hi = f2bf(x);
        o[e] = h ? f2bf(x - bf2f(hi)) : hi;
      }
      int mbO = rowblk >> 2, aq = rowblk & 3;
      size_t unitIdx = (size_t)(mbO * 8 + kt) * 4 + aq;
      *(ushort8*)&xfrag[unitIdx * 4096 + (size_t)((h * 4 + s) * 64 + row64) * 8] = o;
    }
    // fp32 transposed latent for k_idx refinement
    int pix = t >> 2, sub = t & 3;   // 64 pixels x 4 threads
    #pragma unroll
    for (int q = 0; q < 4; ++q) {
      int c = sub * 16 + q * 4;
      float4 v;
      v.x = ls[pix][c]; v.y = ls[pix][c + 1]; v.z = ls[pix][c + 2]; v.w = ls[pix][c + 3];
      *(float4*)&xt[(size_t)(g0 + pix) * DIM + c0 + c] = v;
    }
  } else {
    int e = (bid - 1280) * 256 + t;
    if (e < 6912) {
      int ic = e & 255; int r = e >> 8;
      int kx = r % 3; r /= 3; int ky = r % 3; int oc = r / 3;
      wt[e] = dec_w[((oc * 256 + ic) * 3 + ky) * 3 + kx];
    }
  }
}

// ================== main VQ: 256x256 tile, wave-tile 64x128, R9 1-barrier sync ==================
// Grid 256 = 1 wg/CU. 8 waves as 4(wr:M) x 2(wc:N). Reads 24 b128/tile/wave (vs R9's 36),
// hoisted R9-style ahead of 48-MFMA clusters.
__global__ __launch_bounds__(512, 2) void k_vq(const u16* __restrict__ xfrag,
                                               const u16* __restrict__ bfrag,
                                               const float* __restrict__ cnorm,
                                               u64* __restrict__ partial) {
  __shared__ u16 lds[2][2][4][4096];   // [buf][A/B][unit][8KB] = 128 KiB
  __shared__ float cnl[1024];          // 4 KB
  __shared__ u64 red[256][2];          // 4 KB per-row/per-wc argmin table

  int bid = blockIdx.x;                // 256 wgs = 1/CU
  int xcd = bid & 7, ix = bid >> 3;    // 32 per XCD
  int nbc = xcd * 2 + (ix >> 4);       // 0..15 (1024-code chunk; 2 chunks/XCD -> 2MB B in L2)
  int mb  = ix & 15;                   // 0..15 (256-row X block)

  int tid = threadIdx.x, lane = tid & 63, w = tid >> 6;
  int fr = lane & 15, s = lane >> 4;
  int wr = w >> 1, wc = w & 1;         // wave grid 4M x 2N
  int tid8 = tid * 8;

  const u16* Xb = xfrag + (size_t)mb * 32 * 4096;    // 8 kt x 4 aq units
  const u16* Bb = bfrag + (size_t)nbc * 128 * 4096;  // 32 tiles x 4 units, contiguous

  cnl[tid]       = cnorm[nbc * 1024 + tid];
  cnl[tid + 512] = cnorm[nbc * 1024 + 512 + tid];
  ((u64*)red)[tid] = ~0ull;            // 512 slots
  __syncthreads();

  // ---- prologue: stage tile 0 fully ----
  #pragma unroll
  for (int r = 0; r < 4; ++r) gload16(Xb + (size_t)r * 4096 + tid8, &lds[0][0][r][0] + tid8);
  #pragma unroll
  for (int r = 0; r < 4; ++r) gload16(Bb + (size_t)r * 4096 + tid8, &lds[0][1][r][0] + tid8);
  VM(0); BAR(); FENCE();

  f32x4 acc[4][8] = {};                // [mfr][nf]
  bf16x8 ah[4], al[4], bh[4], bl[4];

  #define READ_A(LA)                                                          \
    _Pragma("unroll")                                                         \
    for (int mfr = 0; mfr < 4; ++mfr) {                                       \
      ah[mfr] = *(const bf16x8*)&(LA)[wr * 4096 + (size_t)((0 + s) * 64 + mfr * 16 + fr) * 8]; \
      al[mfr] = *(const bf16x8*)&(LA)[wr * 4096 + (size_t)((4 + s) * 64 + mfr * 16 + fr) * 8]; \
    }
  #define READ_B(LB, hh)                                                      \
    _Pragma("unroll")                                                         \
    for (int j = 0; j < 4; ++j) {                                             \
      bh[j] = *(const bf16x8*)&(LB)[(wc * 2 + (hh)) * 4096 + (size_t)((0 + s) * 64 + j * 16 + fr) * 8]; \
      bl[j] = *(const bf16x8*)&(LB)[(wc * 2 + (hh)) * 4096 + (size_t)((4 + s) * 64 + j * 16 + fr) * 8]; \
    }
  #define MFMAH(hh)                                                           \
    __builtin_amdgcn_s_setprio(1);                                            \
    _Pragma("unroll")                                                         \
    for (int mfr = 0; mfr < 4; ++mfr) {                                       \
      _Pragma("unroll")                                                       \
      for (int j = 0; j < 4; ++j)                                             \
        acc[mfr][(hh) * 4 + j] = __builtin_amdgcn_mfma_f32_16x16x32_bf16(ah[mfr], bh[j], acc[mfr][(hh) * 4 + j], 0, 0, 0); \
    }                                                                         \
    _Pragma("unroll")                                                         \
    for (int mfr = 0; mfr < 4; ++mfr) {                                       \
      _Pragma("unroll")                                                       \
      for (int j = 0; j < 4; ++j)                                             \
        acc[mfr][(hh) * 4 + j] = __builtin_amdgcn_mfma_f32_16x16x32_bf16(ah[mfr], bl[j], acc[mfr][(hh) * 4 + j], 0, 0, 0); \
    }                                                                         \
    _Pragma("unroll")                                                         \
    for (int mfr = 0; mfr < 4; ++mfr) {                                       \
      _Pragma("unroll")                                                       \
      for (int j = 0; j < 4; ++j)                                             \
        acc[mfr][(hh) * 4 + j] = __builtin_amdgcn_mfma_f32_16x16x32_bf16(al[mfr], bh[j], acc[mfr][(hh) * 4 + j], 0, 0, 0); \
    }                                                                         \
    __builtin_amdgcn_s_setprio(0);
  #define FOLD(pp) {                                                          \
    float cnv[8]; unsigned codev[8];                                          \
    _Pragma("unroll")                                                         \
    for (int nf = 0; nf < 8; ++nf) {                                          \
      cnv[nf] = cnl[(pp) * 256 + wc * 128 + nf * 16 + fr];                    \
      codev[nf] = (unsigned)(nbc * 1024 + (pp) * 256 + wc * 128 + nf * 16 + fr); \
    }                                                                         \
    _Pragma("unroll")                                                         \
    for (int mfr = 0; mfr < 4; ++mfr) {                                       \
      u64 bb[4];                                                              \
      _Pragma("unroll")                                                       \
      for (int rr = 0; rr < 4; ++rr) {                                        \
        u64 m = ~0ull;                                                        \
        _Pragma("unroll")                                                     \
        for (int nf = 0; nf < 8; ++nf) {                                      \
          float val = fmaf(-2.0f, acc[mfr][nf][rr], cnv[nf]);                 \
          u64 key = ((u64)mono(val) << 32) | codev[nf];                       \
          if (key < m) m = key;                                               \
        }                                                                     \
        bb[rr] = m;                                                           \
      }                                                                       \
      _Pragma("unroll")                                                       \
      for (int d = 1; d < 16; d <<= 1) {                                      \
        _Pragma("unroll")                                                     \
        for (int rr = 0; rr < 4; ++rr) {                                      \
          u64 o = __shfl_xor(bb[rr], d, 64);                                  \
          if (o < bb[rr]) bb[rr] = o;                                         \
        }                                                                     \
      }                                                                       \
      if (fr == 0) {                                                          \
        _Pragma("unroll")                                                     \
        for (int rr = 0; rr < 4; ++rr) {                                      \
          int row = wr * 64 + mfr * 16 + s * 4 + rr;                          \
          u64 old = red[row][wc];                                             \
          red[row][wc] = (bb[rr] < old) ? bb[rr] : old;                       \
        }                                                                     \
      }                                                                       \
      _Pragma("unroll")                                                       \
      for (int nf = 0; nf < 8; ++nf)                                          \
        _Pragma("unroll")                                                     \
        for (int rr = 0; rr < 4; ++rr) acc[mfr][nf][rr] = 0.0f;               \
    }                                                                         \
  }

  // ---- 32 K-tiles (4 panels x 8 kt), ONE barrier-pair each (R9-proven sync) ----
  #pragma unroll 1
  for (int tt = 0; tt < 32; ++tt) {
    const int cur = tt & 1, nxt = cur ^ 1;
    const int kt = tt & 7;
    const u16* LA = &lds[cur][0][0][0];
    const u16* LB = &lds[cur][1][0][0];
    READ_A(LA); READ_B(LB, 0);
    if (tt < 31) {
      const u16* SA = Xb + (size_t)((tt + 1) & 7) * 16384;
      const u16* SB = Bb + (size_t)(tt + 1) * 16384;
      #pragma unroll
      for (int r = 0; r < 4; ++r) gload16(SA + (size_t)r * 4096 + tid8, &lds[nxt][0][r][0] + tid8);
      #pragma unroll
      for (int r = 0; r < 4; ++r) gload16(SB + (size_t)r * 4096 + tid8, &lds[nxt][1][r][0] + tid8);
    }
    MFMAH(0);
    READ_B(LB, 1);
    MFMAH(1);
    if (kt == 7) { FOLD(tt >> 3); LGKM0(); }
    VM(0);
    BAR(); FENCE();
  }

  // ---- final: reduce red over wc, write per-row minimum ----
  if (tid < 256) {
    u64 a = red[tid][0], b2 = red[tid][1];
    partial[(size_t)(mb * 256 + tid) * NBLK + nbc] = a < b2 ? a : b2;
  }
}

// ---- per-pixel top-2 reduce + exact fp64 refinement (1 wave/pixel, coalesced) ----
__global__ __launch_bounds__(256) void k_idx(const u64* __restrict__ partial,
                                             const float* __restrict__ xt,
                                             const float* __restrict__ cb,
                                             int* __restrict__ idxo) {
  int p = (blockIdx.x * 256 + threadIdx.x) >> 6;   // pixel id, 1 wave each
  int lane = threadIdx.x & 63;
  u64 v = (lane < NBLK) ? partial[(size_t)p * NBLK + lane] : ~0ull;
  u64 m1 = v;
  #pragma unroll
  for (int d = 1; d < 64; d <<= 1) { u64 o = __shfl_xor(m1, d, 64); if (o < m1) m1 = o; }
  u64 vv = (v == m1) ? ~0ull : v;
  u64 m2 = vv;
  #pragma unroll
  for (int d = 1; d < 64; d <<= 1) { u64 o = __shfl_xor(m2, d, 64); if (o < m2) m2 = o; }
  int n1 = (int)(m1 & 0xFFFFFFFFull);
  int n2 = (int)(m2 & 0xFFFFFFFFull);

  float4 xv = *(const float4*)&xt[(size_t)p * DIM + lane * 4];
  float4 ca = *(const float4*)&cb[(size_t)n1 * DIM + lane * 4];
  float4 cbv = *(const float4*)&cb[(size_t)n2 * DIM + lane * 4];
  double d1, d2;
  {
    double e0 = (double)xv.x - (double)ca.x, e1 = (double)xv.y - (double)ca.y;
    double e2 = (double)xv.z - (double)ca.z, e3 = (double)xv.w - (double)ca.w;
    d1 = e0 * e0 + e1 * e1 + e2 * e2 + e3 * e3;
  }
  {
    double e0 = (double)xv.x - (double)cbv.x, e1 = (double)xv.y - (double)cbv.y;
    double e2 = (double)xv.z - (double)cbv.z, e3 = (double)xv.w - (double)cbv.w;
    d2 = e0 * e0 + e1 * e1 + e2 * e2 + e3 * e3;
  }
  #pragma unroll
  for (int d = 32; d; d >>= 1) {
    d1 += __shfl_down(d1, d, 64);
    d2 += __shfl_down(d2, d, 64);
  }
  if (lane == 0) {
    idxo[p] = (d2 < d1 || (d2 == d1 && n2 < n1)) ? n2 : n1;
  }
}

// ---- gather + 3x3 conv + bias + (x+1)*0.5 + clamp ----
__global__ __launch_bounds__(256) void k_conv(const int* __restrict__ idxo,
                                              const float* __restrict__ cb,
                                              const float* __restrict__ wt,
                                              const float* __restrict__ bias,
                                              float* __restrict__ out) {
  __shared__ int idxl[3][32];
  int y = blockIdx.x, b = blockIdx.y;
  int t = threadIdx.x;
  if (t < 96) {
    int r = t >> 5, px = t & 31;
    int yy = min(max(y + r - 1, 0), 31);
    idxl[r][px] = idxo[b * HW + yy * 32 + px];
  }
  __syncthreads();

  int x = t & 31, icg = t >> 5;
  float a0 = 0.f, a1 = 0.f, a2 = 0.f;
  #pragma unroll
  for (int dy = -1; dy <= 1; dy++) {
    int yy = y + dy;
    if (yy < 0 || yy >= 32) continue;
    #pragma unroll
    for (int dx = -1; dx <= 1; dx++) {
      int xx = x + dx;
      if (xx < 0 || xx >= 32) continue;
      int n = idxl[dy + 1][xx];
      const float4* crow = (const float4*)(cb + (size_t)n * DIM + icg * 32);
      int tap = (dy + 1) * 3 + (dx + 1);
      const float4* w0p = (const float4*)(wt + (size_t)(0 * 9 + tap) * DIM + icg * 32);
      const float4* w1p = (const float4*)(wt + (size_t)(1 * 9 + tap) * DIM + icg * 32);
      const float4* w2p = (const float4*)(wt + (size_t)(2 * 9 + tap) * DIM + icg * 32);
      #pragma unroll
      for (int q = 0; q < 8; q++) {
        float4 qv = crow[q];
        float4 wa = w0p[q];
        a0 = fmaf(qv.x, wa.x, a0); a0 = fmaf(qv.y, wa.y, a0);
        a0 = fmaf(qv.z, wa.z, a0); a0 = fmaf(qv.w, wa.w, a0);
        float4 wb = w1p[q];
        a1 = fmaf(qv.x, wb.x, a1); a1 = fmaf(qv.y, wb.y, a1);
        a1 = fmaf(qv.z, wb.z, a1); a1 = fmaf(qv.w, wb.w, a1);
        float4 wcv = w2p[q];
        a2 = fmaf(qv.x, wcv.x, a2); a2 = fmaf(qv.y, wcv.y, a2);
        a2 = fmaf(qv.z, wcv.z, a2); a2 = fmaf(qv.w, wcv.w, a2);
      }
    }
  }
  __shared__ float red[3][32][8];
  red[0][x][icg] = a0; red[1][x][icg] = a1; red[2][x][icg] = a2;
  __syncthreads();
  if (t < 96) {
    int oc = t >> 5, xo = t & 31;
    float sum = 0.f;
    #pragma unroll
    for (int k = 0; k < 8; k++) sum += red[oc][xo][k];
    sum += bias[oc];
    sum = (sum + 1.0f) * 0.5f;
    sum = fminf(fmaxf(sum, 0.0f), 1.0f);
    out[((size_t)(b * 3 + oc) * 32 + y) * 32 + xo] = sum;
  }
}

extern "C" void kernel_launch(void* const* d_in, const int* in_sizes, int n_in,
                              void* d_out, int out_size, void* d_ws, size_t ws_size,
                              hipStream_t stream) {
  const float* latent = (const float*)d_in[0];   // [4,256,32,32]
  const float* cb     = (const float*)d_in[1];   // [16384,256]
  const float* dec_w  = (const float*)d_in[2];   // [3,256,3,3]
  const float* dec_b  = (const float*)d_in[3];   // [3]
  float* out = (float*)d_out;                    // [4,3,32,32]

  char* ws = (char*)d_ws;
  u64*   partial = (u64*)ws;                      // 512 KB [4096][16]
  float* cnorm   = (float*)(ws + 0x080000);       // 64 KB
  int*   idx     = (int*)  (ws + 0x090000);       // 16 KB
  float* wt      = (float*)(ws + 0x094000);       // 27 KB
  u16*   xfrag   = (u16*)  (ws + 0x100000);       // 4 MB
  u16*   bfrag   = (u16*)  (ws + 0x800000);       // 16 MB -> 0x1800000
  float* xt      = (float*)(ws + 0x1800000);      // 4 MB  -> ends 28 MB

  hipMemsetAsync(cnorm, 0, N_CODE * sizeof(float), stream);
  k_prep<<<dim3(1307), dim3(256), 0, stream>>>(cb, latent, dec_w, bfrag, xfrag, xt, cnorm, wt);
  k_vq  <<<dim3(256),  dim3(512), 0, stream>>>(xfrag, bfrag, cnorm, partial);
  k_idx <<<dim3(1024), dim3(256), 0, stream>>>(partial, xt, cb, idx);
  k_conv<<<dim3(32, 4), dim3(256), 0, stream>>>(idx, cb, wt, dec_b, out);
}